// Round 1
// baseline (410.161 us; speedup 1.0000x reference)
//
#include <hip/hip_runtime.h>
#include <math.h>

// LBP radius=1, n_points=8 on NCHW (16,64,224,224) f32.
// p=0,2,4,6 are exact integer offsets (E,N,W,S neighbors); p=1,3,5,7 are
// bilinear diagonal samples. Bit p weight = 2^p. Zero padding outside.
#define HH 224
#define WW 224
#define TOTAL (16 * 64 * 224 * 224)

struct LbpWeights {
    // w[i] = {(1-fr)(1-fc), (1-fr)fc, fr(1-fc), fr*fc} for p = 1,3,5,7
    float w1[4];
    float w3[4];
    float w5[4];
    float w7[4];
};

__global__ __launch_bounds__(256) void lbp_kernel(const float* __restrict__ x,
                                                  float* __restrict__ out,
                                                  LbpWeights wt) {
    int idx = blockIdx.x * 256 + threadIdx.x;
    if (idx >= TOTAL) return;

    int c = idx % WW;          // column
    int t = idx / WW;
    int r = t % HH;            // row

    const float* p1 = x + idx; // &x[bc][r][c]

    bool rm = (r > 0), rp = (r < HH - 1);
    bool cm = (c > 0), cp = (c < WW - 1);

    // 3x3 neighborhood with zero padding (matches jnp.pad constant-0)
    float n00 = (rm && cm) ? p1[-WW - 1] : 0.0f;
    float n01 = rm         ? p1[-WW]     : 0.0f;
    float n02 = (rm && cp) ? p1[-WW + 1] : 0.0f;
    float n10 = cm         ? p1[-1]      : 0.0f;
    float n11 =              p1[0];
    float n12 = cp         ? p1[1]       : 0.0f;
    float n20 = (rp && cm) ? p1[WW - 1]  : 0.0f;
    float n21 = rp         ? p1[WW]      : 0.0f;
    float n22 = (rp && cp) ? p1[WW + 1]  : 0.0f;

    // Diagonal bilinear samples. MUST match numpy f32 arithmetic bit-exactly:
    // per-term f32 rounding, left-to-right sum, no FMA contraction.
    float v1, v3, v5, v7;
    {
#pragma clang fp contract(off)
        // p=1: r0=-1,c0=0 -> win = n01,n02,n11,n12
        v1 = ((wt.w1[0] * n01 + wt.w1[1] * n02) + wt.w1[2] * n11) + wt.w1[3] * n12;
        // p=3: r0=-1,c0=-1 -> win = n00,n01,n10,n11
        v3 = ((wt.w3[0] * n00 + wt.w3[1] * n01) + wt.w3[2] * n10) + wt.w3[3] * n11;
        // p=5: r0=0,c0=-1 -> win = n10,n11,n20,n21
        v5 = ((wt.w5[0] * n10 + wt.w5[1] * n11) + wt.w5[2] * n20) + wt.w5[3] * n21;
        // p=7: r0=0,c0=0 -> win = n11,n12,n21,n22
        v7 = ((wt.w7[0] * n11 + wt.w7[1] * n12) + wt.w7[2] * n21) + wt.w7[3] * n22;
    }

    int m = 0;
    m |= (n12 >= n11) ? 1   : 0;  // p=0: (0,+1) exact
    m |= (v1  >= n11) ? 2   : 0;  // p=1 diagonal
    m |= (n01 >= n11) ? 4   : 0;  // p=2: (-1,0) exact
    m |= (v3  >= n11) ? 8   : 0;  // p=3 diagonal
    m |= (n10 >= n11) ? 16  : 0;  // p=4: (0,-1) exact
    m |= (v5  >= n11) ? 32  : 0;  // p=5 diagonal
    m |= (n21 >= n11) ? 64  : 0;  // p=6: (+1,0) exact
    m |= (v7  >= n11) ? 128 : 0;  // p=7 diagonal

    out[idx] = (float)m;  // exact int->f32 (<=255)
}

extern "C" void kernel_launch(void* const* d_in, const int* in_sizes, int n_in,
                              void* d_out, int out_size, void* d_ws, size_t ws_size,
                              hipStream_t stream) {
    (void)in_sizes; (void)n_in; (void)d_ws; (void)ws_size; (void)out_size;
    const float* x = (const float*)d_in[0];
    float* out = (float*)d_out;

    // Replicate np.round(-R*sin(ang), 8) = rint(v*1e8)/1e8 in double; any
    // 1-ulp libm sin/cos difference is absorbed by the rint. Weights are the
    // float64 products rounded to f32 (NEP-50 weak-scalar semantics).
    LbpWeights wt;
    float* slots[4] = {wt.w1, wt.w3, wt.w5, wt.w7};
    const int diag_p[4] = {1, 3, 5, 7};
    for (int i = 0; i < 4; i++) {
        int p = diag_p[i];
        double ang = (2.0 * M_PI * (double)p) / 8.0;
        double dr = rint(-sin(ang) * 1e8) / 1e8;
        double dc = rint( cos(ang) * 1e8) / 1e8;
        double r0 = floor(dr), c0 = floor(dc);
        double fr = dr - r0, fc = dc - c0;
        slots[i][0] = (float)((1.0 - fr) * (1.0 - fc));
        slots[i][1] = (float)((1.0 - fr) * fc);
        slots[i][2] = (float)(fr * (1.0 - fc));
        slots[i][3] = (float)(fr * fc);
    }

    const int total = TOTAL;
    const int block = 256;
    const int grid = (total + block - 1) / block;  // 200704
    lbp_kernel<<<grid, block, 0, stream>>>(x, out, wt);
}

// Round 2
// 371.834 us; speedup vs baseline: 1.1031x; 1.1031x over previous
//
#include <hip/hip_runtime.h>
#include <math.h>

// LBP radius=1, n_points=8 on NCHW (16,64,224,224) f32.
// Register-blocked: each thread computes a 4x4 pixel tile.
// p=0,2,4,6 exact neighbor compares; p=1,3,5,7 bilinear diagonals (bit-exact
// vs numpy f32: per-term rounding, left-to-right sum, no FMA contraction).
#define HH 224
#define WW 224
#define PLANES (16 * 64)
#define TILES_X (WW / 4)          // 56
#define TILES_PER_PLANE (TILES_X * (HH / 4))  // 3136
#define TOTAL_THREADS (PLANES * TILES_PER_PLANE)  // 3,211,264

struct LbpWeights {
    float w1[4];
    float w3[4];
    float w5[4];
    float w7[4];
};

__global__ __launch_bounds__(256) void lbp_kernel(const float* __restrict__ x,
                                                  float* __restrict__ out,
                                                  LbpWeights wt) {
    int tid = blockIdx.x * 256 + threadIdx.x;

    int plane = tid / TILES_PER_PLANE;
    int t = tid - plane * TILES_PER_PLANE;
    int tr = t / TILES_X;
    int tc = t - tr * TILES_X;
    int r0 = tr * 4, c0 = tc * 4;

    const float* pb = x + (size_t)plane * (HH * WW);

    // a[i][k]: window rows r0-1..r0+4 (i=0..5), cols c0-1..c0+4 (k=0..5),
    // zero outside the image (matches constant-0 padding).
    float a[6][6];
    bool cm = (c0 > 0), cp = (c0 + 4 < WW);
#pragma unroll
    for (int i = 0; i < 6; i++) {
        int rr = r0 - 1 + i;
        if (rr >= 0 && rr < HH) {
            const float* rp = pb + rr * WW + c0;
            float4 v = *(const float4*)rp;
            a[i][1] = v.x; a[i][2] = v.y; a[i][3] = v.z; a[i][4] = v.w;
            a[i][0] = cm ? rp[-1] : 0.0f;
            a[i][5] = cp ? rp[4]  : 0.0f;
        } else {
#pragma unroll
            for (int k = 0; k < 6; k++) a[i][k] = 0.0f;
        }
    }

    float* ob = out + (size_t)plane * (HH * WW) + r0 * WW + c0;

#pragma unroll
    for (int j = 0; j < 4; j++) {
        float res[4];
#pragma unroll
        for (int k = 0; k < 4; k++) {
            float ctr = a[j + 1][k + 1];
            float n00 = a[j][k],     n01 = a[j][k + 1],     n02 = a[j][k + 2];
            float n10 = a[j + 1][k],                        n12 = a[j + 1][k + 2];
            float n20 = a[j + 2][k], n21 = a[j + 2][k + 1], n22 = a[j + 2][k + 2];

            float v1, v3, v5, v7;
            {
#pragma clang fp contract(off)
                // p=1: r0=-1,c0=0 -> (n01, n02, ctr, n12)
                v1 = ((wt.w1[0] * n01 + wt.w1[1] * n02) + wt.w1[2] * ctr) + wt.w1[3] * n12;
                // p=3: r0=-1,c0=-1 -> (n00, n01, n10, ctr)
                v3 = ((wt.w3[0] * n00 + wt.w3[1] * n01) + wt.w3[2] * n10) + wt.w3[3] * ctr;
                // p=5: r0=0,c0=-1 -> (n10, ctr, n20, n21)
                v5 = ((wt.w5[0] * n10 + wt.w5[1] * ctr) + wt.w5[2] * n20) + wt.w5[3] * n21;
                // p=7: r0=0,c0=0 -> (ctr, n12, n21, n22)
                v7 = ((wt.w7[0] * ctr + wt.w7[1] * n12) + wt.w7[2] * n21) + wt.w7[3] * n22;
            }

            int m = 0;
            m |= (n12 >= ctr) ? 1   : 0;
            m |= (v1  >= ctr) ? 2   : 0;
            m |= (n01 >= ctr) ? 4   : 0;
            m |= (v3  >= ctr) ? 8   : 0;
            m |= (n10 >= ctr) ? 16  : 0;
            m |= (v5  >= ctr) ? 32  : 0;
            m |= (n21 >= ctr) ? 64  : 0;
            m |= (v7  >= ctr) ? 128 : 0;
            res[k] = (float)m;
        }
        *(float4*)(ob + j * WW) = make_float4(res[0], res[1], res[2], res[3]);
    }
}

extern "C" void kernel_launch(void* const* d_in, const int* in_sizes, int n_in,
                              void* d_out, int out_size, void* d_ws, size_t ws_size,
                              hipStream_t stream) {
    (void)in_sizes; (void)n_in; (void)d_ws; (void)ws_size; (void)out_size;
    const float* x = (const float*)d_in[0];
    float* out = (float*)d_out;

    // Replicate np.round(-R*sin(ang), 8) = rint(v*1e8)/1e8 in double; weights
    // are float64 products rounded to f32 (NEP-50 weak-scalar semantics).
    LbpWeights wt;
    float* slots[4] = {wt.w1, wt.w3, wt.w5, wt.w7};
    const int diag_p[4] = {1, 3, 5, 7};
    for (int i = 0; i < 4; i++) {
        int p = diag_p[i];
        double ang = (2.0 * M_PI * (double)p) / 8.0;
        double dr = rint(-sin(ang) * 1e8) / 1e8;
        double dc = rint( cos(ang) * 1e8) / 1e8;
        double r0 = floor(dr), c0 = floor(dc);
        double fr = dr - r0, fc = dc - c0;
        slots[i][0] = (float)((1.0 - fr) * (1.0 - fc));
        slots[i][1] = (float)((1.0 - fr) * fc);
        slots[i][2] = (float)(fr * (1.0 - fc));
        slots[i][3] = (float)(fr * fc);
    }

    const int block = 256;
    const int grid = TOTAL_THREADS / block;  // 12544, exact
    lbp_kernel<<<grid, block, 0, stream>>>(x, out, wt);
}